// Round 7
// baseline (461.594 us; speedup 1.0000x reference)
//
#include <hip/hip_runtime.h>

#define NN 20000
#define NE 640000
#define NR 8
#define NB 8
#define HID 256
#define KPOI 12
#define KTIME 2880
#define KROAD 128
#define NK (NN * NR)   // 160000 (dst,rel) keys
#define SPLITK 5
#define KCH (KTIME / SPLITK)   // 576 = 9 x 64

typedef __attribute__((ext_vector_type(8))) short bf8_t;   // 8 bf16 = 4 VGPR
typedef __attribute__((ext_vector_type(4))) float f4_t;

__device__ inline unsigned short f2bf(float f) {  // RNE f32->bf16
  unsigned int u = __float_as_uint(f);
  u += 0x7FFF + ((u >> 16) & 1);
  return (unsigned short)(u >> 16);
}
__device__ inline float bf2f(unsigned short h) {
  return __uint_as_float((unsigned int)h << 16);
}

// -------- WT[l][r][o][i] = sum_b coef_l[r,b]*basis_l[b][i][o] (bf16), l=0,1 --
__global__ __launch_bounds__(256) void make_WT12(
    const float* __restrict__ coef1, const float* __restrict__ basis1,
    const float* __restrict__ coef2, const float* __restrict__ basis2,
    unsigned short* __restrict__ WT) {   // [2*NR][256][256]
  int idx = blockIdx.x * 256 + threadIdx.x;   // < 2*NR*65536
  int r = idx >> 16;          // 0..15
  int o = (idx >> 8) & 255;
  int i = idx & 255;
  const float* coef  = (r < NR) ? coef1 : coef2;
  const float* basis = (r < NR) ? basis1 : basis2;
  int rr = r & 7;
  float acc = 0.f;
#pragma unroll
  for (int b = 0; b < NB; ++b)
    acc += coef[rr * NB + b] * basis[b * HID * HID + i * HID + o];
  WT[idx] = f2bf(acc);
}

// -------- transpose both loop weights: L[l][c][r] = w_l[r][c] (bf16) --------
__global__ __launch_bounds__(256) void transp_LW(
    const float* __restrict__ w1, const float* __restrict__ w2,
    unsigned short* __restrict__ L1, unsigned short* __restrict__ L2) {
  int idx = blockIdx.x * 256 + threadIdx.x;   // < 2*65536
  int sel = idx >> 16;
  int j = idx & 65535;
  int r = j >> 8, c = j & 255;
  const float* in = sel ? w2 : w1;
  unsigned short* out = sel ? L2 : L1;
  out[c * HID + r] = f2bf(in[j]);
}

// ---------------- transpose + convert: out[c][r] = in[r][c] (bf16) ---------
__global__ __launch_bounds__(256) void transp_bf16(const float* __restrict__ in,
                                                   unsigned short* __restrict__ out,
                                                   int R, int Cc) {
  int idx = blockIdx.x * 256 + threadIdx.x;
  if (idx >= R * Cc) return;
  int r = idx / Cc, c = idx - r * Cc;
  out[(size_t)c * R + r] = f2bf(in[idx]);
}

// ---------------- small f32 GEMM -> bf16 out (poi / road projections) ------
#define BK 16
template<int BM, int BN, int TM, int TN>
__global__ __launch_bounds__(256) void sgemm_bf(
    int M, int Nn, int K,
    const float* __restrict__ A, int lda,
    const float* __restrict__ B, int ldb,
    const float* __restrict__ bias,
    unsigned short* __restrict__ C, int ldc)
{
  constexpr int SA = BM + 4;
  constexpr int SB = BN + 4;
  __shared__ float As[BK * SA];
  __shared__ float Bs[BK * SB];
  const int tid = threadIdx.x;
  const int brow = blockIdx.x * BM;
  const int bcol = blockIdx.y * BN;
  constexpr int TCOLS = BN / TN;
  const int row0 = (tid / TCOLS) * TM;
  const int col0 = (tid % TCOLS) * TN;

  float acc[TM][TN] = {};

  for (int kb = 0; kb < K; kb += BK) {
    constexpr int AIT = (BM * 4) / 256;
#pragma unroll
    for (int it = 0; it < AIT; ++it) {
      int i = tid + it * 256;
      int r = i >> 2, q = (i & 3) * 4;
      int grow = brow + r, gk = kb + q;
      if (grow < M && gk + 3 < K) {
        float4 v = *(const float4*)(A + (size_t)grow * lda + gk);
        As[(q + 0) * SA + r] = v.x;
        As[(q + 1) * SA + r] = v.y;
        As[(q + 2) * SA + r] = v.z;
        As[(q + 3) * SA + r] = v.w;
      } else {
#pragma unroll
        for (int j = 0; j < 4; ++j)
          As[(q + j) * SA + r] =
              (grow < M && gk + j < K) ? A[(size_t)grow * lda + gk + j] : 0.f;
      }
    }
    constexpr int BIT = (BN * 4) / 256;
#pragma unroll
    for (int it = 0; it < BIT; ++it) {
      int i = tid + it * 256;
      int k = i / (BN / 4), cq = (i % (BN / 4)) * 4;
      int gk = kb + k, gc = bcol + cq;
      float4 v = {0.f, 0.f, 0.f, 0.f};
      if (gk < K) {
        if (gc + 3 < Nn) {
          v = *(const float4*)(B + (size_t)gk * ldb + gc);
        } else {
#pragma unroll
          for (int j = 0; j < 4; ++j)
            if (gc + j < Nn) (&v.x)[j] = B[(size_t)gk * ldb + gc + j];
        }
      }
      *(float4*)(&Bs[k * SB + cq]) = v;
    }
    __syncthreads();
#pragma unroll
    for (int kk = 0; kk < BK; ++kk) {
      float a[TM], b[TN];
#pragma unroll
      for (int i = 0; i < TM; i += 4)
        *(float4*)(&a[i]) = *(const float4*)(&As[kk * SA + row0 + i]);
#pragma unroll
      for (int j = 0; j < TN; j += 4)
        *(float4*)(&b[j]) = *(const float4*)(&Bs[kk * SB + col0 + j]);
#pragma unroll
      for (int i = 0; i < TM; ++i)
#pragma unroll
        for (int j = 0; j < TN; ++j)
          acc[i][j] += a[i] * b[j];
    }
    __syncthreads();
  }

  float bcache[TN];
#pragma unroll
  for (int j = 0; j < TN; ++j)
    bcache[j] = bias ? bias[bcol + col0 + j] : 0.f;
#pragma unroll
  for (int i = 0; i < TM; ++i) {
    int row = brow + row0 + i;
    if (row >= M) continue;
#pragma unroll
    for (int j = 0; j < TN; ++j) {
      int col = bcol + col0 + j;
      if (col < Nn)
        C[(size_t)row * ldc + col] = f2bf(acc[i][j] + bcache[j]);
    }
  }
}

// ---------------- split-K time GEMM: TP[kc] = time_dist[:, kc-chunk] @ TWT^T
// grid (625, SPLITK); block 256 = 4 waves
__global__ __launch_bounds__(256) void mfma_time_sk(
    const float* __restrict__ A,            // [NN][2880] f32
    const unsigned short* __restrict__ BT,  // [128][2880] bf16
    float* __restrict__ TP)                 // [SPLITK][NN][128]
{
  __shared__ __align__(16) char ldsA[32 * 128];
  __shared__ __align__(16) char ldsB[128 * 128];
  const int tid = threadIdx.x;
  const int lane = tid & 63;
  const int w = tid >> 6;            // 0..3 -> col block w*32
  const int brow = blockIdx.x * 32;
  const int kb0 = blockIdx.y * KCH;

  f4_t acc[2][2];
#pragma unroll
  for (int i = 0; i < 2; ++i)
#pragma unroll
    for (int j = 0; j < 2; ++j) acc[i][j] = (f4_t){0.f, 0.f, 0.f, 0.f};

  for (int kb = kb0; kb < kb0 + KCH; kb += 64) {
    {  // A: 32 rows x 64 k, f32 -> bf16
      int r = tid >> 3, c8 = tid & 7;
      const float* ap = A + (size_t)(brow + r) * KTIME + kb + c8 * 8;
      f4_t v0 = *(const f4_t*)ap;
      f4_t v1 = *(const f4_t*)(ap + 4);
      unsigned short hh[8];
#pragma unroll
      for (int j = 0; j < 4; ++j) { hh[j] = f2bf(v0[j]); hh[4 + j] = f2bf(v1[j]); }
      *(bf8_t*)(ldsA + r * 128 + ((c8 * 16) ^ ((r & 7) << 4))) = *(bf8_t*)hh;
    }
#pragma unroll
    for (int it = 0; it < 4; ++it) {  // B: 128 rows x 64 k
      int slot = tid + it * 256;
      int r = slot >> 3, c8 = slot & 7;
      bf8_t v = *(const bf8_t*)(BT + (size_t)r * KTIME + kb + c8 * 8);
      *(bf8_t*)(ldsB + r * 128 + ((c8 * 16) ^ ((r & 7) << 4))) = v;
    }
    __syncthreads();
#pragma unroll
    for (int ks = 0; ks < 2; ++ks) {
      const int kbyte = ks * 64 + (lane >> 4) * 16;
      bf8_t af[2], bfr[2];
#pragma unroll
      for (int mi = 0; mi < 2; ++mi) {
        int m = mi * 16 + (lane & 15);
        af[mi] = *(const bf8_t*)(ldsA + m * 128 + (kbyte ^ ((m & 7) << 4)));
      }
#pragma unroll
      for (int ni = 0; ni < 2; ++ni) {
        int n = w * 32 + ni * 16 + (lane & 15);
        bfr[ni] = *(const bf8_t*)(ldsB + n * 128 + (kbyte ^ ((n & 7) << 4)));
      }
#pragma unroll
      for (int mi = 0; mi < 2; ++mi)
#pragma unroll
        for (int ni = 0; ni < 2; ++ni)
          acc[mi][ni] = __builtin_amdgcn_mfma_f32_16x16x32_bf16(
              af[mi], bfr[ni], acc[mi][ni], 0, 0, 0);
    }
    __syncthreads();
  }

  float* tp = TP + (size_t)blockIdx.y * NN * 128;
  const int rq = (lane >> 4) * 4;
  const int cl = lane & 15;
#pragma unroll
  for (int ni = 0; ni < 2; ++ni) {
    int c = w * 32 + ni * 16 + cl;
#pragma unroll
    for (int mi = 0; mi < 2; ++mi) {
#pragma unroll
      for (int j = 0; j < 4; ++j) {
        int row = brow + mi * 16 + rq + j;
        tp[(size_t)row * 128 + c] = acc[mi][ni][j];
      }
    }
  }
}

// ---------------- time finish: featb[:,64:192] = bf16(sum_k TP + bias) -----
__global__ __launch_bounds__(256) void time_finish(
    const float* __restrict__ TP, const float* __restrict__ bias,
    unsigned short* __restrict__ featb) {
  int i = blockIdx.x * 256 + threadIdx.x;   // over NN*32 float4 groups
  if (i >= NN * 32) return;
  int row = i >> 5, c4 = (i & 31) * 4;
  f4_t s = *(const f4_t*)(TP + (size_t)row * 128 + c4);
#pragma unroll
  for (int k = 1; k < SPLITK; ++k) {
    f4_t v = *(const f4_t*)(TP + (size_t)k * NN * 128 + (size_t)row * 128 + c4);
    s.x += v.x; s.y += v.y; s.z += v.z; s.w += v.w;
  }
  f4_t b = *(const f4_t*)(bias + c4);
  unsigned short h[4] = {f2bf(s.x + b.x), f2bf(s.y + b.y),
                         f2bf(s.z + b.z), f2bf(s.w + b.w)};
  *(ushort4*)(featb + (size_t)row * 256 + 64 + c4) = *(ushort4*)h;
}

// ---------------- CSR segment aggregation into Z slices --------------------
// one wave per (rel q, dst d): Z[q*NN+d] = sum of hin[src] rows (bf16)
__global__ __launch_bounds__(256) void agg_k(
    const int* __restrict__ offs, const unsigned short* __restrict__ ssrc,
    const unsigned short* __restrict__ hin, unsigned short* __restrict__ Z) {
  int w = (blockIdx.x * 256 + threadIdx.x) >> 6;
  int lane = threadIdx.x & 63;
  if (w >= NR * NN) return;
  int q = w / NN;
  int d = w - q * NN;
  int lo = offs[d * NR + q];
  int hi = offs[d * NR + q + 1];
  f4_t az = {0.f, 0.f, 0.f, 0.f};
  int e = lo;
  for (; e + 4 <= hi; e += 4) {
    int s0 = ssrc[e], s1 = ssrc[e + 1], s2 = ssrc[e + 2], s3 = ssrc[e + 3];
    ushort4 u0 = *(const ushort4*)(hin + (size_t)s0 * HID + lane * 4);
    ushort4 u1 = *(const ushort4*)(hin + (size_t)s1 * HID + lane * 4);
    ushort4 u2 = *(const ushort4*)(hin + (size_t)s2 * HID + lane * 4);
    ushort4 u3 = *(const ushort4*)(hin + (size_t)s3 * HID + lane * 4);
    az.x += (bf2f(u0.x) + bf2f(u1.x)) + (bf2f(u2.x) + bf2f(u3.x));
    az.y += (bf2f(u0.y) + bf2f(u1.y)) + (bf2f(u2.y) + bf2f(u3.y));
    az.z += (bf2f(u0.z) + bf2f(u1.z)) + (bf2f(u2.z) + bf2f(u3.z));
    az.w += (bf2f(u0.w) + bf2f(u1.w)) + (bf2f(u2.w) + bf2f(u3.w));
  }
  for (; e < hi; ++e) {
    int s = ssrc[e];
    ushort4 u = *(const ushort4*)(hin + (size_t)s * HID + lane * 4);
    az.x += bf2f(u.x); az.y += bf2f(u.y);
    az.z += bf2f(u.z); az.w += bf2f(u.w);
  }
  unsigned short hz[4] = {f2bf(az.x), f2bf(az.y), f2bf(az.z), f2bf(az.w)};
  *(ushort4*)(Z + (size_t)w * HID + lane * 4) = *(ushort4*)hz;
}

// ---------------- layer GEMM: acc = self@LWT + sum_r Z_r@W_r^T -------------
// block = 32 rows x 256 cols, 8 waves (512 thr); grid 625 (NN/32 exact).
// EPI 0: C = acc + bias (f32).  EPI 2: hb = bf16(relu(acc + bias)).
template<int EPI>
__global__ __launch_bounds__(512) void gemm_acc(
    const unsigned short* __restrict__ hbufA,  // self slice [NN][256]
    const unsigned short* __restrict__ Z,      // [NR][NN][256]
    const unsigned short* __restrict__ WT,     // [NR][256][256]
    const unsigned short* __restrict__ LWT,    // [256][256]
    const float* __restrict__ bias,
    float* __restrict__ C, unsigned short* __restrict__ hb)
{
  __shared__ __align__(16) char At[32 * 512];    // 16 KB, swizzled
  __shared__ __align__(16) char Bt[256 * 128];   // 32 KB, swizzled
  const int tid = threadIdx.x;
  const int lane = tid & 63;
  const int w = tid >> 6;        // 0..7
  const int wr = w >> 2;         // 0..1: rows wr*16..+15
  const int wc = w & 3;          // 0..3: cols wc*64..+63
  const int brow = blockIdx.x * 32;

  f4_t acc[4];
#pragma unroll
  for (int i = 0; i < 4; ++i) acc[i] = (f4_t){0.f, 0.f, 0.f, 0.f};

#pragma unroll 1
  for (int s = 0; s < NR + 1; ++s) {
    const unsigned short* Asrc = (s == 0) ? hbufA : Z + (size_t)(s - 1) * NN * HID;
    const unsigned short* Wsrc = (s == 0) ? LWT : WT + (size_t)(s - 1) * HID * HID;
    // ---- stage A tile: 32 rows x 256 bf16 (1024 x 16B slots, 2 iters) ----
#pragma unroll
    for (int it = 0; it < 2; ++it) {
      int slot = tid + it * 512;
      int r = slot >> 5, c16 = slot & 31;
      bf8_t v = *(const bf8_t*)(Asrc + (size_t)(brow + r) * HID + c16 * 8);
      *(bf8_t*)(At + r * 512 + ((c16 * 16) ^ ((r & 7) << 4))) = v;
    }
    __syncthreads();
#pragma unroll 1
    for (int kc = 0; kc < 4; ++kc) {
#pragma unroll
      for (int it = 0; it < 4; ++it) {  // stage W chunk: 256 n-rows x 64 k
        int slot = tid + it * 512;
        int n = slot >> 3, c8 = slot & 7;
        bf8_t v = *(const bf8_t*)(Wsrc + (size_t)n * HID + kc * 64 + c8 * 8);
        *(bf8_t*)(Bt + n * 128 + ((c8 * 16) ^ ((n & 7) << 4))) = v;
      }
      __syncthreads();
#pragma unroll
      for (int ks = 0; ks < 2; ++ks) {
        const int kbyte = ks * 64 + (lane >> 4) * 16;
        int m = wr * 16 + (lane & 15);
        bf8_t af = *(const bf8_t*)(
            At + m * 512 + ((kc * 128 + kbyte) ^ ((m & 7) << 4)));
#pragma unroll
        for (int ni = 0; ni < 4; ++ni) {
          int n = wc * 64 + ni * 16 + (lane & 15);
          bf8_t bfr = *(const bf8_t*)(Bt + n * 128 + (kbyte ^ ((n & 7) << 4)));
          acc[ni] = __builtin_amdgcn_mfma_f32_16x16x32_bf16(af, bfr, acc[ni], 0, 0, 0);
        }
      }
      __syncthreads();
    }
  }

  // ---- epilogue: D col = lane&15, row = (lane>>4)*4 + j; NN%32==0 ----
  const int rq = (lane >> 4) * 4;
  const int cl = lane & 15;
#pragma unroll
  for (int ni = 0; ni < 4; ++ni) {
    int c = wc * 64 + ni * 16 + cl;
    float bv = bias[c];
#pragma unroll
    for (int j = 0; j < 4; ++j) {
      int row = brow + wr * 16 + rq + j;
      size_t o = (size_t)row * 256 + c;
      float v = acc[ni][j] + bv;
      if (EPI == 0) C[o] = v;
      else          hb[o] = f2bf(fmaxf(v, 0.f));
    }
  }
}

// ---------------- CSR build: key = dst*NR + etype ----------------
__global__ __launch_bounds__(256) void hist_k(const int* __restrict__ dst,
                                              const int* __restrict__ et,
                                              int* __restrict__ counts) {
  int e = blockIdx.x * 256 + threadIdx.x;
  if (e < NE) atomicAdd(&counts[dst[e] * NR + et[e]], 1);
}

__global__ __launch_bounds__(256) void scan_block(const int* __restrict__ counts,
                                                  int* __restrict__ offs,
                                                  int* __restrict__ bsums) {
  __shared__ int sh[256];
  int base = blockIdx.x * 1024;
  int t = threadIdx.x;
  int v[4];
  int s = 0;
#pragma unroll
  for (int j = 0; j < 4; ++j) {
    int idx = base + t * 4 + j;
    v[j] = (idx < NK) ? counts[idx] : 0;
    s += v[j];
  }
  sh[t] = s;
  __syncthreads();
  for (int off = 1; off < 256; off <<= 1) {
    int x = (t >= off) ? sh[t - off] : 0;
    __syncthreads();
    sh[t] += x;
    __syncthreads();
  }
  int run = sh[t] - s;
#pragma unroll
  for (int j = 0; j < 4; ++j) {
    int idx = base + t * 4 + j;
    if (idx < NK) offs[idx] = run;
    run += v[j];
  }
  if (t == 255) bsums[blockIdx.x] = sh[255];
}

__global__ __launch_bounds__(256) void scan_bsums(int* __restrict__ bsums, int nblk) {
  __shared__ int sh[256];
  int t = threadIdx.x;
  int own = (t < nblk) ? bsums[t] : 0;
  sh[t] = own;
  __syncthreads();
  for (int off = 1; off < 256; off <<= 1) {
    int x = (t >= off) ? sh[t - off] : 0;
    __syncthreads();
    sh[t] += x;
    __syncthreads();
  }
  int ex = sh[t] - own;
  if (t < nblk) bsums[t] = ex;
}

// writes final offs AND cursor copy (saves a separate copy pass)
__global__ __launch_bounds__(256) void add_base(int* __restrict__ offs,
                                                const int* __restrict__ bsums,
                                                int* __restrict__ cursor) {
  int idx = blockIdx.x * 256 + threadIdx.x;
  if (idx < NK) {
    int v = offs[idx] + bsums[idx >> 10];
    offs[idx] = v;
    cursor[idx] = v;
  }
  if (idx == NK) offs[NK] = NE;
}

__global__ __launch_bounds__(256) void fill_k(const int* __restrict__ src,
                                              const int* __restrict__ dst,
                                              const int* __restrict__ et,
                                              int* __restrict__ cursor,
                                              unsigned short* __restrict__ ssrc) {
  int e = blockIdx.x * 256 + threadIdx.x;
  if (e < NE) {
    int key = dst[e] * NR + et[e];
    int p = atomicAdd(&cursor[key], 1);
    ssrc[p] = (unsigned short)src[e];
  }
}

extern "C" void kernel_launch(void* const* d_in, const int* in_sizes, int n_in,
                              void* d_out, int out_size, void* d_ws, size_t ws_size,
                              hipStream_t stream) {
  const int*   srcp      = (const int*)d_in[0];
  const int*   dstp      = (const int*)d_in[1];
  const int*   etypep    = (const int*)d_in[2];
  const float* poi_dist  = (const float*)d_in[3];
  const float* time_dist = (const float*)d_in[4];
  const float* road_feat = (const float*)d_in[5];
  const float* poi_w     = (const float*)d_in[6];
  const float* poi_b     = (const float*)d_in[7];
  const float* time_w    = (const float*)d_in[8];
  const float* time_b    = (const float*)d_in[9];
  const float* road_w    = (const float*)d_in[10];
  const float* road_b    = (const float*)d_in[11];
  const float* basis1    = (const float*)d_in[12];
  const float* coef1     = (const float*)d_in[13];
  const float* loop_w1   = (const float*)d_in[14];
  const float* bias1     = (const float*)d_in[15];
  const float* basis2    = (const float*)d_in[16];
  const float* coef2     = (const float*)d_in[17];
  const float* loop_w2   = (const float*)d_in[18];
  const float* bias2     = (const float*)d_in[19];

  float* out = (float*)d_out;

  // ws layout (bytes), total ~148.4 MB (ws_size ~921 MB):
  //   WT1  bf16 @ 0           (1,048,576)   layer-1 relation W^T
  //   WT2  bf16 @ 1,048,576   (1,048,576)   layer-2 relation W^T
  //   LWT1 bf16 @ 2,097,152   (131,072)
  //   LWT2 bf16 @ 2,228,224   (131,072)
  //   TWT  bf16 @ 2,359,296   (737,280)     time_w^T
  //   hbuf bf16 @ 3,096,576   (10,240,000)  featb in L1; relu(h1) bf16 in L2
  //   Z    bf16 @ 13,336,576  (81,920,000)  8 slices (N x 256 each)
  //   TP   f32  @ 95,256,576  (51,200,000)  split-K time partials
  //   offs      @ 146,456,576 (640,016)
  //   bsums     @ 147,096,592 (1,024)
  //   ssrc u16  @ 147,097,616 (1,280,000)
  // aliases (dead before host region's first real write):
  //   counts -> Z region, cursor -> TP region
  char* ws = (char*)d_ws;
  unsigned short* WT1    = (unsigned short*)(ws);
  unsigned short* WT2    = (unsigned short*)(ws + 1048576);
  unsigned short* LWT1   = (unsigned short*)(ws + 2097152);
  unsigned short* LWT2   = (unsigned short*)(ws + 2228224);
  unsigned short* TWT    = (unsigned short*)(ws + 2359296);
  unsigned short* hbuf   = (unsigned short*)(ws + 3096576);
  unsigned short* Z      = (unsigned short*)(ws + 13336576);
  float*          TP     = (float*)(ws + 95256576);
  int*            offs   = (int*)  (ws + 146456576);
  int*            bsums  = (int*)  (ws + 147096592);
  unsigned short* ssrc   = (unsigned short*)(ws + 147097616);
  int*            counts = (int*)Z;
  int*            cursor = (int*)TP;

  dim3 blk(256);
  const int MG64 = (NN + 63) / 64;  // 313

  // ---- CSR build (aliases dead before Z/TP first writes) ----
  hipMemsetAsync(counts, 0, NK * sizeof(int), stream);
  hist_k<<<NE / 256, blk, 0, stream>>>(dstp, etypep, counts);
  scan_block<<<(NK + 1023) / 1024, blk, 0, stream>>>(counts, offs, bsums);
  scan_bsums<<<1, blk, 0, stream>>>(bsums, (NK + 1023) / 1024);
  add_base<<<(NK + 1 + 255) / 256, blk, 0, stream>>>(offs, bsums, cursor);
  fill_k<<<NE / 256, blk, 0, stream>>>(srcp, dstp, etypep, cursor, ssrc);

  // ---- weight preprocessing (all up front) ----
  transp_LW<<<2 * HID * HID / 256, blk, 0, stream>>>(loop_w1, loop_w2, LWT1, LWT2);
  transp_bf16<<<(KTIME * 128 + 255) / 256, blk, 0, stream>>>(time_w, TWT, KTIME, 128);
  make_WT12<<<2 * NR * HID * HID / 256, blk, 0, stream>>>(coef1, basis1,
                                                          coef2, basis2, WT1);

  // ---- input projections -> hbuf (N x 256 bf16) ----
  sgemm_bf<64, 64, 4, 4><<<dim3(MG64, 1), blk, 0, stream>>>(
      NN, 64, KPOI, poi_dist, KPOI, poi_w, 64, poi_b, hbuf + 0, HID);
  mfma_time_sk<<<dim3(NN / 32, SPLITK), blk, 0, stream>>>(time_dist, TWT, TP);
  time_finish<<<(NN * 32 + 255) / 256, blk, 0, stream>>>(TP, time_b, hbuf);
  sgemm_bf<64, 64, 4, 4><<<dim3(MG64, 1), blk, 0, stream>>>(
      NN, 64, KROAD, road_feat, KROAD, road_w, 64, road_b, hbuf + 192, HID);

  // ---- layer 1: hbuf = bf16(relu(bias1 + self@LW1 + sum_r Z_r@W_r)) ----
  agg_k<<<(NR * NN) / 4, blk, 0, stream>>>(offs, ssrc, hbuf, Z);
  gemm_acc<2><<<NN / 32, 512, 0, stream>>>(hbuf, Z, WT1, LWT1, bias1,
                                           nullptr, hbuf);

  // ---- layer 2: out = bias2 + self@LW2 + sum_r Z_r@W_r (f32) ----
  agg_k<<<(NR * NN) / 4, blk, 0, stream>>>(offs, ssrc, hbuf, Z);
  gemm_acc<0><<<NN / 32, 512, 0, stream>>>(hbuf, Z, WT2, LWT2, bias2,
                                           out, nullptr);
}